// Round 1
// baseline (129.787 us; speedup 1.0000x reference)
//
#include <hip/hip_runtime.h>
#include <cmath>

// CriticSNN forward: BATCH=65536, STATE_DIM=6, HIDDEN=128, NUM_STEPS=8, OUT=1
// One wave (64 lanes) per batch element; lane l owns neurons l and l+64.
// Spikes are binary -> ballots; matmuls become masked column sums from LDS.

constexpr int BATCH = 65536;
constexpr int HID   = 128;
constexpr int SDIM  = 6;
constexpr int NSTEP = 8;
constexpr int BLOCK = 1024;                         // 16 waves/block
constexpr int GRID  = 256;                          // 1 block per CU
constexpr int WAVES_TOTAL = GRID * (BLOCK / 64);    // 4096
constexpr int ELEMS_PER_WAVE = BATCH / WAVES_TOTAL; // 16

__global__ __launch_bounds__(BLOCK) void snn_fwd(
    const float* __restrict__ state,
    const float* __restrict__ w_fc1,
    const float* __restrict__ w_rec1,
    const float* __restrict__ w_fc2,
    const float* __restrict__ w_rec2,
    const float* __restrict__ w_mean,
    const float* __restrict__ w_std,
    const float* __restrict__ p_alpha1, const float* __restrict__ p_beta1,
    const float* __restrict__ p_thr1,
    const float* __restrict__ p_alpha2, const float* __restrict__ p_beta2,
    const float* __restrict__ p_thr2,
    float* __restrict__ out)
{
    // Packed transposed weights: entry (j, l) = float2(w[l][j], w[l+64][j])
    // stored at index j*64 + (l ^ (j & 63))  (XOR swizzle: conflict-free reads,
    // coalesced global->LDS staging writes).
    __shared__ float2 ld_rec1[HID * 64];   // 64 KiB
    __shared__ float2 ld_fc2 [HID * 64];   // 64 KiB
    __shared__ float2 ld_fc1 [SDIM * 64];  // 3 KiB  (no swizzle)
    __shared__ float  ld_wm[HID];
    __shared__ float  ld_wsd[HID];

    const int tid = threadIdx.x;

    // ---- stage w_rec1 / w_fc2 (coalesced reads, swizzled b64 writes) ----
    for (int v = tid; v < HID * 64; v += BLOCK) {
        const int l = v >> 7;        // 0..63
        const int j = v & 127;       // 0..127 (consecutive lanes -> consecutive j)
        const int pos = (j << 6) | (l ^ (j & 63));
        ld_rec1[pos] = make_float2(w_rec1[l * HID + j], w_rec1[(l + 64) * HID + j]);
        ld_fc2 [pos] = make_float2(w_fc2 [l * HID + j], w_fc2 [(l + 64) * HID + j]);
    }
    // ---- stage w_fc1 (tiny) ----
    for (int v = tid; v < SDIM * 64; v += BLOCK) {
        const int k = v >> 6, l = v & 63;
        ld_fc1[(k << 6) | l] = make_float2(w_fc1[l * SDIM + k], w_fc1[(l + 64) * SDIM + k]);
    }
    if (tid < HID)               ld_wm [tid]        = w_mean[tid];
    else if (tid < 2 * HID)      ld_wsd[tid - HID]  = w_std [tid - HID];

    const float a1 = fminf(fmaxf(p_alpha1[0], 0.f), 1.f);
    const float b1 = fminf(fmaxf(p_beta1 [0], 0.f), 1.f);
    const float a2 = fminf(fmaxf(p_alpha2[0], 0.f), 1.f);
    const float b2 = fminf(fmaxf(p_beta2 [0], 0.f), 1.f);
    const float t1 = p_thr1[0];
    const float t2 = p_thr2[0];

    __syncthreads();

    const int lane  = tid & 63;
    const int gwave = blockIdx.x * (BLOCK / 64) + (tid >> 6);

    for (int e = 0; e < ELEMS_PER_WAVE; ++e) {
        const int b = gwave + WAVES_TOTAL * e;

        // cur1_in = state[b] @ w_fc1.T  (constant across steps)
        float cur_a = 0.f, cur_b = 0.f;
        #pragma unroll
        for (int k = 0; k < SDIM; ++k) {
            const float s = state[b * SDIM + k];          // wave-broadcast
            const float2 w = ld_fc1[(k << 6) | lane];
            cur_a = fmaf(s, w.x, cur_a);
            cur_b = fmaf(s, w.y, cur_b);
        }

        float syn1a = 0.f, syn1b = 0.f, mem1a = 0.f, mem1b = 0.f;
        float syn2a = 0.f, syn2b = 0.f, mem2a = 0.f, mem2b = 0.f;
        bool  spk1a = false, spk1b = false, spk2a = false, spk2b = false;
        float cnt_a = 0.f, cnt_b = 0.f;
        unsigned long long m1a = 0ull, m1b = 0ull, m2a = 0ull, m2b = 0ull;

        #pragma unroll 1
        for (int t = 0; t < NSTEP; ++t) {
            // ----- layer 1: rec1 contribution from PREVIOUS spk1 -----
            float r_a = 0.f, r_b = 0.f;
            unsigned long long m = m1a;
            while (m) {
                const int j = __builtin_ctzll(m); m &= m - 1;
                const float2 w = ld_rec1[(j << 6) | (lane ^ j)];
                r_a += w.x; r_b += w.y;
            }
            m = m1b;
            while (m) {
                const int j0 = __builtin_ctzll(m); m &= m - 1;
                const int j = j0 + 64;
                const float2 w = ld_rec1[(j << 6) | (lane ^ j0)];
                r_a += w.x; r_b += w.y;
            }
            syn1a = fmaf(a1, syn1a, cur_a + r_a);
            syn1b = fmaf(a1, syn1b, cur_b + r_b);
            mem1a = fmaf(b1, mem1a, syn1a) - (spk1a ? t1 : 0.f);
            mem1b = fmaf(b1, mem1b, syn1b) - (spk1b ? t1 : 0.f);
            spk1a = (mem1a - t1) > 0.f;
            spk1b = (mem1b - t1) > 0.f;
            m1a = __ballot(spk1a);
            m1b = __ballot(spk1b);

            // ----- layer 2: fc2 from NEW spk1, rec2 from OLD spk2 -----
            float f_a = 0.f, f_b = 0.f;
            m = m1a;
            while (m) {
                const int j = __builtin_ctzll(m); m &= m - 1;
                const float2 w = ld_fc2[(j << 6) | (lane ^ j)];
                f_a += w.x; f_b += w.y;
            }
            m = m1b;
            while (m) {
                const int j0 = __builtin_ctzll(m); m &= m - 1;
                const int j = j0 + 64;
                const float2 w = ld_fc2[(j << 6) | (lane ^ j0)];
                f_a += w.x; f_b += w.y;
            }
            // spk2 is extremely rare: read w_rec2 straight from global when it fires
            m = m2a;
            while (m) {
                const int j = __builtin_ctzll(m); m &= m - 1;
                f_a += w_rec2[lane * HID + j];
                f_b += w_rec2[(lane + 64) * HID + j];
            }
            m = m2b;
            while (m) {
                const int j = __builtin_ctzll(m) + 64; m &= m - 1;
                f_a += w_rec2[lane * HID + j];
                f_b += w_rec2[(lane + 64) * HID + j];
            }
            syn2a = fmaf(a2, syn2a, f_a);
            syn2b = fmaf(a2, syn2b, f_b);
            mem2a = fmaf(b2, mem2a, syn2a) - (spk2a ? t2 : 0.f);
            mem2b = fmaf(b2, mem2b, syn2b) - (spk2b ? t2 : 0.f);
            spk2a = (mem2a - t2) > 0.f;
            spk2b = (mem2b - t2) > 0.f;
            m2a = __ballot(spk2a);
            m2b = __ballot(spk2b);
            cnt_a += spk2a ? 1.f : 0.f;
            cnt_b += spk2b ? 1.f : 0.f;
        }

        // ----- head: dot(avg_spikes, w_mean/w_std) + activations -----
        const float avg_a = cnt_a * (1.f / (float)NSTEP);
        const float avg_b = cnt_b * (1.f / (float)NSTEP);
        float dm = avg_a * ld_wm [lane] + avg_b * ld_wm [lane + 64];
        float ds = avg_a * ld_wsd[lane] + avg_b * ld_wsd[lane + 64];
        #pragma unroll
        for (int off = 32; off > 0; off >>= 1) {
            dm += __shfl_xor(dm, off, 64);
            ds += __shfl_xor(ds, off, 64);
        }
        if (lane == 0) {
            out[b]         = tanhf(dm);
            const float sg = 1.f / (1.f + expf(-(ds + 2.f)));
            out[BATCH + b] = 1.9f * sg + 0.1f;
        }
    }
}

extern "C" void kernel_launch(void* const* d_in, const int* in_sizes, int n_in,
                              void* d_out, int out_size, void* d_ws, size_t ws_size,
                              hipStream_t stream) {
    (void)in_sizes; (void)n_in; (void)d_ws; (void)ws_size; (void)out_size;
    snn_fwd<<<GRID, BLOCK, 0, stream>>>(
        (const float*)d_in[0],  // state
        (const float*)d_in[1],  // w_fc1
        (const float*)d_in[2],  // w_rec1
        (const float*)d_in[3],  // w_fc2
        (const float*)d_in[4],  // w_rec2
        (const float*)d_in[5],  // w_mean
        (const float*)d_in[6],  // w_std
        (const float*)d_in[7],  // alpha1
        (const float*)d_in[8],  // beta1
        (const float*)d_in[9],  // thr1
        (const float*)d_in[10], // alpha2
        (const float*)d_in[11], // beta2
        (const float*)d_in[12], // thr2
        (float*)d_out);
}